// Round 10
// baseline (176.799 us; speedup 1.0000x reference)
//
#include <hip/hip_runtime.h>
#include <stdint.h>

// Fused MLP decode, MFMA f16. Wave = 64 points (4 sub-tiles of 16), 4-wave wg.
// Weights in workgroup LDS (fragment-order, conflict-free b128). Feature
// fragments generated in MFMA A-layout via one Chebyshev chain. Sub-tiles
// processed in software-interleaved PAIRS with double-buffered per-wave H:
// st1's gather/features/L0 hides st0's H write->read LDS round-trip.
// ZERO barriers in the loop (wave-private H, in-order DS pipe).
// NOTE: __launch_bounds__ has NO min-waves arg (",4" caused 64-VGPR spills).

typedef _Float16 half8  __attribute__((ext_vector_type(8)));
typedef _Float16 half4v __attribute__((ext_vector_type(4)));
typedef _Float16 half2v __attribute__((ext_vector_type(2)));
typedef float f32x4 __attribute__((ext_vector_type(4)));

#define LOG2E 1.44269504088896340736f
#define BASE_LOGIT -0.84729786038720367f   // log(0.3/0.7)
#define CSANMAX 28700.0f
#define IC_VAL 8610.0f                     // 0.3 * 28700

__device__ __forceinline__ float fast_exp2(float x) { return __builtin_amdgcn_exp2f(x); }
__device__ __forceinline__ float fast_rcp(float x)  { return __builtin_amdgcn_rcpf(x); }
__device__ __forceinline__ float sigf(float x)  { return fast_rcp(1.0f + fast_exp2(-LOG2E * x)); }
__device__ __forceinline__ void silu2(float x0, float x1, float& y0, float& y1) {
  const float d0 = 1.0f + fast_exp2(-LOG2E * x0);
  const float d1 = 1.0f + fast_exp2(-LOG2E * x1);
  const float r  = fast_rcp(d0 * d1);
  y0 = x0 * d1 * r;
  y1 = x1 * d0 * r;
}
__device__ __forceinline__ half2v pkh(float a, float b) {
  return __builtin_bit_cast(half2v, __builtin_amdgcn_cvt_pkrtz(a, b));
}

union H8 { half8 v8; half2v v2[4]; };
union H4 { half4v v4; half2v v2[2]; };

template <int CTRL>
__device__ __forceinline__ float dpp_radd(float x) {
  int yi = __builtin_amdgcn_update_dpp(0, __builtin_bit_cast(int, x), CTRL, 0xF, 0xF, false);
  return x + __builtin_bit_cast(float, yi);
}
__device__ __forceinline__ float row_sum16(float x) {
  x = dpp_radd<0xB1>(x);    // quad_perm [1,0,3,2]
  x = dpp_radd<0x4E>(x);    // quad_perm [2,3,0,1]
  x = dpp_radd<0x141>(x);   // row_half_mirror
  x = dpp_radd<0x140>(x);   // row_mirror
  return x;
}

__global__ __launch_bounds__(256) void mlp_kernel(
    const int* __restrict__ tix, const float* __restrict__ rho,
    const float* __restrict__ emb, const float* __restrict__ W0,
    const float* __restrict__ b0, const float* __restrict__ W1,
    const float* __restrict__ b1, const float* __restrict__ Wout,
    const float* __restrict__ bout, float* __restrict__ out, int ngroups)
{
  // Weights: fragment-order swizzle [s][t][lane][8 f16] -> 8 KB per layer.
  __shared__ __align__(16) _Float16 Wlds0[2][4][64][8];
  __shared__ __align__(16) _Float16 Wlds1[2][4][64][8];
  // H: per-wave DOUBLE buffer, stride 72 halfs (144 B). 4*2*2304 = 18432 B.
  __shared__ __align__(16) _Float16 ldsH[4][2][16][72];

  const int tid  = threadIdx.x;
  const int wid  = tid >> 6;
  const int lane = tid & 63;
  const int m    = lane & 15;
  const int q    = lane >> 4;

  // ---- init: wave 0 builds the swizzled weight fragments ----
  // content B[k=s*32+q*8+j][n=t*16+m]; A-op for L0 (=> W^T), B-op for L1.
  // L0 feature rows PERMUTED: k-window 32..63 = [cos1..8|sin1..8|rho,b0(1.0),0pad]
  if (wid == 0) {
#pragma unroll
    for (int t = 0; t < 4; ++t) {
#pragma unroll
      for (int s = 0; s < 2; ++s) {
        half8 f0, f1;
#pragma unroll
        for (int j = 0; j < 8; ++j) {
          const int k = s * 32 + q * 8 + j;
          const int n = t * 16 + m;
          float v0;
          if (k < 32) {
            v0 = W0[k * 64 + n];
          } else {
            const int kn = k - 32;
            v0 = (kn < 16) ? W0[(33 + kn) * 64 + n]
               : (kn == 16) ? W0[32 * 64 + n]
               : (kn == 17) ? b0[n] : 0.0f;
          }
          f0[j] = (_Float16)v0;
          f1[j] = (_Float16)W1[k * 64 + n];
        }
        *(half8*)&Wlds0[s][t][lane][0] = f0;
        *(half8*)&Wlds1[s][t][lane][0] = f1;
      }
    }
  }

  float b1n[4], woutm[4];
#pragma unroll
  for (int t = 0; t < 4; ++t) {
    b1n[t]   = b1[t * 16 + m];
    woutm[t] = Wout[t * 16 + m];
  }
  const float boutBL = bout[0] + BASE_LOGIT;

  __syncthreads();   // weights visible (only barrier in kernel)

  const f32x4 z = {0.0f, 0.0f, 0.0f, 0.0f};
  const int gstride = gridDim.x * 4;

  int g = blockIdx.x * 4 + wid;
  if (g >= ngroups) return;          // after the barrier: safe

  int   tiL = tix[g * 64 + lane];
  float rh  = rho[g * 64 + lane];

  for (; g < ngroups; g += gstride) {
    const int gbase = g * 64;

    const int gn = (g + gstride < ngroups) ? (g + gstride) : g;
    const int   tiLn = tix[gn * 64 + lane];
    const float rhn  = rho[gn * 64 + lane];

    float dcar = 0.0f;  // raw output dot for point gbase+lane

#pragma unroll
    for (int p = 0; p < 2; ++p) {
      const int st0 = 2 * p, st1 = 2 * p + 1;
      _Float16 (*Hb0)[72] = ldsH[wid][0];
      _Float16 (*Hb1)[72] = ldsH[wid][1];

      // ---- hoisted: L0 weight fragments for this pair (lgkm overlaps VALU) ----
      half8 w0A[4], w0B[4];
#pragma unroll
      for (int t = 0; t < 4; ++t) {
        w0A[t] = *(const half8*)&Wlds0[0][t][lane][0];
        w0B[t] = *(const half8*)&Wlds0[1][t][lane][0];
      }

      // ---- both gathers issued up front ----
      const int tim0 = __shfl(tiL, st0 * 16 + m, 64);
      const int tim1 = __shfl(tiL, st1 * 16 + m, 64);
      const float* er0 = emb + (size_t)min(max(tim0 - 1, 0), 510) * 32 + q * 8;
      const float* er1 = emb + (size_t)min(max(tim1 - 1, 0), 510) * 32 + q * 8;
      const f32x4 e00 = *(const f32x4*)er0;
      const f32x4 e01 = *(const f32x4*)(er0 + 4);
      const f32x4 e10 = *(const f32x4*)er1;
      const f32x4 e11 = *(const f32x4*)(er1 + 4);

      // ---- feature fragments for both sub-tiles (Chebyshev in A-layout) ----
      H8 X1a, X1b;
#pragma unroll
      for (int u = 0; u < 2; ++u) {
        const int stu = 2 * p + u;
        const float rhp = __shfl(rh, stu * 16 + m, 64);
        const float rev = 0.5f * rhp;  // v_sin/v_cos take revolutions
        const float c1  = __builtin_amdgcn_cosf(rev);
        const float s1f = __builtin_amdgcn_sinf(rev);
        const float tc  = 2.0f * c1;
        const float x1v = (q == 0) ? c1 : s1f;
        const float x0v = (q == 0) ? 1.0f : 0.0f;
        const float x2v = tc * x1v - x0v;
        const float x3v = tc * x2v - x1v;
        const float x4v = tc * x3v - x2v;
        const float x5v = tc * x4v - x3v;
        const float x6v = tc * x5v - x4v;
        const float x7v = tc * x6v - x5v;
        const float x8v = tc * x7v - x6v;
        H8 X;
        X.v2[0] = pkh(x1v, x2v);
        X.v2[1] = pkh(x3v, x4v);
        X.v2[2] = pkh(x5v, x6v);
        X.v2[3] = pkh(x7v, x8v);
        const half2v z2 = {};
        const half2v pr = pkh(rhp, 1.0f);
        const bool hi = (q >= 2);
        X.v2[0] = hi ? ((q == 2) ? pr : z2) : X.v2[0];
        X.v2[1] = hi ? z2 : X.v2[1];
        X.v2[2] = hi ? z2 : X.v2[2];
        X.v2[3] = hi ? z2 : X.v2[3];
        if (u == 0) X1a = X; else X1b = X;
      }
      H8 X0a, X0b;
      X0a.v2[0] = pkh(e00[0], e00[1]); X0a.v2[1] = pkh(e00[2], e00[3]);
      X0a.v2[2] = pkh(e01[0], e01[1]); X0a.v2[3] = pkh(e01[2], e01[3]);
      X0b.v2[0] = pkh(e10[0], e10[1]); X0b.v2[1] = pkh(e10[2], e10[3]);
      X0b.v2[2] = pkh(e11[0], e11[1]); X0b.v2[3] = pkh(e11[2], e11[3]);

      // ---- L0 MFMAs for BOTH sub-tiles (independent chains) ----
      f32x4 accA[4], accB[4];
#pragma unroll
      for (int t = 0; t < 4; ++t) {
        f32x4 a = __builtin_amdgcn_mfma_f32_16x16x32_f16(w0A[t], X0a.v8, z, 0, 0, 0);
        accA[t] = __builtin_amdgcn_mfma_f32_16x16x32_f16(w0B[t], X1a.v8, a, 0, 0, 0);
        f32x4 b = __builtin_amdgcn_mfma_f32_16x16x32_f16(w0A[t], X0b.v8, z, 0, 0, 0);
        accB[t] = __builtin_amdgcn_mfma_f32_16x16x32_f16(w0B[t], X1b.v8, b, 0, 0, 0);
      }
      // ---- silu + H writes (A then B; independent buffers) ----
#pragma unroll
      for (int t = 0; t < 4; ++t) {
        float s0, s1v, s2, s3;
        silu2(accA[t][0], accA[t][1], s0, s1v);
        silu2(accA[t][2], accA[t][3], s2, s3);
        H4 hh; hh.v2[0] = pkh(s0, s1v); hh.v2[1] = pkh(s2, s3);
        *(half4v*)&Hb0[m][t * 16 + q * 4] = hh.v4;
      }
#pragma unroll
      for (int t = 0; t < 4; ++t) {
        float s0, s1v, s2, s3;
        silu2(accB[t][0], accB[t][1], s0, s1v);
        silu2(accB[t][2], accB[t][3], s2, s3);
        H4 hh; hh.v2[0] = pkh(s0, s1v); hh.v2[1] = pkh(s2, s3);
        *(half4v*)&Hb1[m][t * 16 + q * 4] = hh.v4;
      }

      // ---- hoisted: L1 weights, then both H reads ----
      half8 w1A[4], w1B[4];
#pragma unroll
      for (int t = 0; t < 4; ++t) {
        w1A[t] = *(const half8*)&Wlds1[0][t][lane][0];
        w1B[t] = *(const half8*)&Wlds1[1][t][lane][0];
      }
      const half8 Y0a = *(const half8*)&Hb0[m][q * 8];
      const half8 Y1a = *(const half8*)&Hb0[m][32 + q * 8];
      const half8 Y0b = *(const half8*)&Hb1[m][q * 8];
      const half8 Y1b = *(const half8*)&Hb1[m][32 + q * 8];

      // ---- L1 MFMAs for both ----
#pragma unroll
      for (int t = 0; t < 4; ++t) {
        const f32x4 binit = {b1n[t], b1n[t], b1n[t], b1n[t]};
        f32x4 a = __builtin_amdgcn_mfma_f32_16x16x32_f16(Y0a, w1A[t], binit, 0, 0, 0);
        accA[t] = __builtin_amdgcn_mfma_f32_16x16x32_f16(Y1a, w1B[t], a, 0, 0, 0);
        f32x4 b = __builtin_amdgcn_mfma_f32_16x16x32_f16(Y0b, w1A[t], binit, 0, 0, 0);
        accB[t] = __builtin_amdgcn_mfma_f32_16x16x32_f16(Y1b, w1B[t], b, 0, 0, 0);
      }

      // ---- epilogues (A then B) ----
#pragma unroll
      for (int u = 0; u < 2; ++u) {
        const f32x4* acc = (u == 0) ? accA : accB;
        const int stu = 2 * p + u;
        float dot0 = 0.0f, dot1 = 0.0f, dot2 = 0.0f, dot3 = 0.0f;
#pragma unroll
        for (int t = 0; t < 4; ++t) {
          float s0, s1v, s2, s3;
          silu2(acc[t][0], acc[t][1], s0, s1v);
          silu2(acc[t][2], acc[t][3], s2, s3);
          dot0 = fmaf(s0,  woutm[t], dot0);
          dot1 = fmaf(s1v, woutm[t], dot1);
          dot2 = fmaf(s2,  woutm[t], dot2);
          dot3 = fmaf(s3,  woutm[t], dot3);
        }
        dot0 = row_sum16(dot0);
        dot1 = row_sum16(dot1);
        dot2 = row_sum16(dot2);
        dot3 = row_sum16(dot3);
        const float dsel = (m & 2) ? ((m & 1) ? dot3 : dot2) : ((m & 1) ? dot1 : dot0);
        const float dg = __shfl(dsel, (m >> 2) * 16 + (m & 3), 64);
        dcar = (q == stu) ? dg : dcar;
      }
    }

    // ---- epilogue: one coalesced 256B store per group per wave ----
    const float theta = sigf(dcar + boutBL);
    out[gbase + lane] = (tiL == 0) ? IC_VAL : theta * CSANMAX;

    tiL = tiLn; rh = rhn;
  }
}

extern "C" void kernel_launch(void* const* d_in, const int* in_sizes, int n_in,
                              void* d_out, int out_size, void* d_ws, size_t ws_size,
                              hipStream_t stream) {
  const int*   tix  = (const int*)d_in[0];
  const float* rho  = (const float*)d_in[1];
  const float* emb  = (const float*)d_in[2];
  const float* W0   = (const float*)d_in[3];
  const float* b0   = (const float*)d_in[4];
  const float* W1   = (const float*)d_in[5];
  const float* b1   = (const float*)d_in[6];
  const float* Wout = (const float*)d_in[7];
  const float* bout = (const float*)d_in[8];
  float* outp = (float*)d_out;

  const int n       = in_sizes[0];   // 2,000,000 (divisible by 64)
  const int ngroups = n / 64;        // 31,250 groups of 64 points

  // 4-wave blocks; LDS 34816 B -> 4 blocks/CU -> 16 waves/CU
  int grid = 1024;
  const int maxg = (ngroups + 3) / 4;
  if (grid > maxg) grid = maxg;
  mlp_kernel<<<dim3(grid), dim3(256), 0, stream>>>(
      tix, rho, emb, W0, b0, W1, b1, Wout, bout, outp, ngroups);
}